// Round 4
// baseline (2317.015 us; speedup 1.0000x reference)
//
#include <hip/hip_runtime.h>

#define B_ 16
#define CN_ 22
#define T_ 1000
#define EXP_ 300
#define FCH_ 150
#define SPD_ 100
#define LDSTR 108

// workspace layout (bytes)
static constexpr unsigned long long OFF_M2   = 0ull;
static constexpr unsigned long long OFF_HCAT = 65536ull;
static constexpr unsigned long long OFF_XC   = OFF_HCAT + 28800000ull;
static constexpr unsigned long long OFF_COV  = OFF_XC   + 6400000ull;
static constexpr unsigned long long OFF_T1   = OFF_COV  + 640000ull;
static constexpr unsigned long long OFF_P    = OFF_T1   + 640000ull;

struct PrepPtrs  { const float* w1[3]; const float* w2[3]; const float* w3[3]; const float* w4[3]; };
struct FrontPtrs { const float* g1[3]; const float* b1[3]; const float* w5[3];
                   const float* g2[3]; const float* b2[3]; int K[3]; };

__device__ __forceinline__ float block_sum(float v, float* sbuf) {
  #pragma unroll
  for (int off = 32; off > 0; off >>= 1) v += __shfl_down(v, off, 64);
  const int wid  = threadIdx.x >> 6;
  const int lane = threadIdx.x & 63;
  const int nw   = blockDim.x >> 6;
  if (lane == 0) sbuf[wid] = v;
  __syncthreads();
  float r = 0.f;
  for (int w = 0; w < nw; ++w) r += sbuf[w];
  __syncthreads();
  return r;
}

// ---------------------------------------------------------------------------
// K1: fold conv(3,1) + w2-expand + max-norm depthwise spatial + pointwise
// ---------------------------------------------------------------------------
__global__ __launch_bounds__(256) void k_prep(PrepPtrs pp, float* __restrict__ M2) {
  const int beta = blockIdx.x;
  __shared__ float w3r[EXP_*CN_];
  __shared__ float M[FCH_*CN_];
  const float* w1 = pp.w1[beta];
  const float* w2 = pp.w2[beta];
  const float* w3 = pp.w3[beta];
  const float* w4 = pp.w4[beta];

  for (int g = threadIdx.x; g < EXP_; g += 256) {
    float s = 0.f;
    for (int c = 0; c < CN_; ++c) { float w = w3[g*CN_ + c]; s += w*w; }
    float n = sqrtf(s);
    float scale = fminf(1.f, 1.f/(n + 1e-12f)) * w2[g];
    for (int c = 0; c < CN_; ++c) w3r[g*CN_ + c] = w3[g*CN_ + c] * scale;
  }
  __syncthreads();
  for (int idx = threadIdx.x; idx < FCH_*CN_; idx += 256) {
    int o = idx / CN_, c = idx - o*CN_;
    float acc = 0.f;
    for (int g = 0; g < EXP_; ++g) acc += w4[o*EXP_ + g] * w3r[g*CN_ + c];
    M[idx] = acc;
  }
  __syncthreads();
  const float k0 = w1[0], k1 = w1[1], k2 = w1[2];
  for (int idx = threadIdx.x; idx < FCH_*CN_; idx += 256) {
    int c = idx % CN_;
    float v = k1 * M[idx];
    if (c > 0)       v += k2 * M[idx - 1];
    if (c < CN_ - 1) v += k0 * M[idx + 1];
    M2[beta*FCH_*CN_ + idx] = v;
  }
}

// ---------------------------------------------------------------------------
// K2: per (beta,b,o) row: h = M2 row @ x[b] -> LN -> depthwise conv K -> LN
// ---------------------------------------------------------------------------
__global__ __launch_bounds__(256) void k_front(const float* __restrict__ x,
                                               const float* __restrict__ M2,
                                               FrontPtrs fp,
                                               float* __restrict__ hcat) {
  const int wg   = blockIdx.x;
  const int beta = wg / (B_*FCH_);
  const int rem  = wg - beta*(B_*FCH_);
  const int b    = rem / FCH_;
  const int o    = rem - b*FCH_;
  const int K    = fp.K[beta];
  const int Kh   = K >> 1;

  __shared__ float m2[CN_];
  __shared__ float hb2[T_];
  __shared__ float w5s[80];
  __shared__ float red[8];

  if (threadIdx.x < CN_) m2[threadIdx.x] = M2[(beta*FCH_ + o)*CN_ + threadIdx.x];
  if (threadIdx.x < K)   w5s[threadIdx.x] = fp.w5[beta][o*K + threadIdx.x];
  __syncthreads();

  const float* xb = x + (size_t)b*CN_*T_;
  float hv[4];
  float psum = 0.f;
  #pragma unroll
  for (int e = 0; e < 4; ++e) {
    int t = threadIdx.x + 256*e;
    float acc = 0.f;
    if (t < T_) {
      #pragma unroll
      for (int c = 0; c < CN_; ++c) acc += m2[c] * xb[c*T_ + t];
    }
    hv[e] = acc; psum += acc;
  }
  float mean = block_sum(psum, red) * (1.f/T_);
  float pv = 0.f;
  #pragma unroll
  for (int e = 0; e < 4; ++e) { int t = threadIdx.x + 256*e; if (t < T_) { float d = hv[e]-mean; pv += d*d; } }
  float var = block_sum(pv, red) * (1.f/T_);
  float inv = rsqrtf(var + 1e-5f);
  const float* g1 = fp.g1[beta]; const float* b1 = fp.b1[beta];
  #pragma unroll
  for (int e = 0; e < 4; ++e) { int t = threadIdx.x + 256*e; if (t < T_) hb2[t] = (hv[e]-mean)*inv*g1[t] + b1[t]; }
  __syncthreads();

  float cv[4];
  float ps2 = 0.f;
  #pragma unroll
  for (int e = 0; e < 4; ++e) {
    int t = threadIdx.x + 256*e;
    float acc = 0.f;
    if (t < T_) {
      int lo = t - Kh;
      for (int k = 0; k < K; ++k) {
        int tt = lo + k;
        float hvv = (tt >= 0 && tt < T_) ? hb2[tt] : 0.f;
        acc += hvv * w5s[k];
      }
    }
    cv[e] = acc; ps2 += acc;
  }
  float mean2 = block_sum(ps2, red) * (1.f/T_);
  float pv2 = 0.f;
  #pragma unroll
  for (int e = 0; e < 4; ++e) { int t = threadIdx.x + 256*e; if (t < T_) { float d = cv[e]-mean2; pv2 += d*d; } }
  float var2 = block_sum(pv2, red) * (1.f/T_);
  float inv2 = rsqrtf(var2 + 1e-5f);
  const float* g2 = fp.g2[beta]; const float* b2 = fp.b2[beta];
  float* hrow = hcat + ((size_t)b*(3*FCH_) + beta*FCH_ + o)*T_;
  #pragma unroll
  for (int e = 0; e < 4; ++e) { int t = threadIdx.x + 256*e; if (t < T_) hrow[t] = (cv[e]-mean2)*inv2*g2[t] + b2[t]; }
}

// ---------------------------------------------------------------------------
// K3: h_s = w_sconv @ hcat per b, subtract per-row time mean, store xc.
// ---------------------------------------------------------------------------
__global__ __launch_bounds__(256) void k_sconv(const float* __restrict__ hcat,
                                               const float* __restrict__ wsc,
                                               float* __restrict__ xc) {
  const int b  = blockIdx.x / 10;
  const int s0 = (blockIdx.x % 10) * 10;
  __shared__ float ws[10*450];
  __shared__ float red[8];
  for (int idx = threadIdx.x; idx < 4500; idx += 256) {
    int s = idx / 450, i = idx - s*450;
    ws[idx] = wsc[(s0+s)*450 + i];
  }
  __syncthreads();
  float acc[10][4];
  #pragma unroll
  for (int s = 0; s < 10; ++s)
    #pragma unroll
    for (int e = 0; e < 4; ++e) acc[s][e] = 0.f;
  const float* hb = hcat + (size_t)b*450*T_;
  for (int i = 0; i < 450; ++i) {
    float xv[4];
    #pragma unroll
    for (int e = 0; e < 4; ++e) { int t = threadIdx.x + 256*e; xv[e] = (t < T_) ? hb[(size_t)i*T_ + t] : 0.f; }
    #pragma unroll
    for (int s = 0; s < 10; ++s) {
      float w = ws[s*450 + i];
      #pragma unroll
      for (int e = 0; e < 4; ++e) acc[s][e] += w * xv[e];
    }
  }
  for (int s = 0; s < 10; ++s) {
    float mu = block_sum(acc[s][0]+acc[s][1]+acc[s][2]+acc[s][3], red) * (1.f/T_);
    float* xr = xc + ((size_t)b*SPD_ + s0 + s)*T_;
    #pragma unroll
    for (int e = 0; e < 4; ++e) { int t = threadIdx.x + 256*e; if (t < T_) xr[t] = acc[s][e] - mu; }
  }
}

// ---------------------------------------------------------------------------
// K4a: cov = xc xc^T /999 + 1e-4 I
// ---------------------------------------------------------------------------
__global__ __launch_bounds__(256) void k_cov(const float* __restrict__ xc, float* __restrict__ cov) {
  const int b  = blockIdx.x / 5;
  const int j0 = (blockIdx.x % 5) * 20;
  __shared__ __align__(16) float xst[SPD_*100];
  const int it = threadIdx.x / 10;
  const int jj = threadIdx.x - it*10;
  const bool act = threadIdx.x < 250;
  double a64[4][2] = {{0.0,0.0},{0.0,0.0},{0.0,0.0},{0.0,0.0}};
  for (int ch = 0; ch < 10; ++ch) {
    __syncthreads();
    const int tc0 = ch*100;
    for (int idx = threadIdx.x; idx < SPD_*100; idx += 256) {
      int row = idx / 100, tt = idx - row*100;
      xst[idx] = xc[((size_t)b*SPD_ + row)*T_ + tc0 + tt];
    }
    __syncthreads();
    if (act) {
      float a32[4][2] = {{0,0},{0,0},{0,0},{0,0}};
      for (int t4 = 0; t4 < 100; t4 += 4) {
        float4 xi[4], xj[2];
        #pragma unroll
        for (int r = 0; r < 4; ++r) xi[r] = *(const float4*)&xst[(it + 25*r)*100 + t4];
        #pragma unroll
        for (int s = 0; s < 2; ++s) xj[s] = *(const float4*)&xst[(j0 + jj + 10*s)*100 + t4];
        #pragma unroll
        for (int r = 0; r < 4; ++r)
          #pragma unroll
          for (int s = 0; s < 2; ++s)
            a32[r][s] += xi[r].x*xj[s].x + xi[r].y*xj[s].y + xi[r].z*xj[s].z + xi[r].w*xj[s].w;
      }
      #pragma unroll
      for (int r = 0; r < 4; ++r)
        #pragma unroll
        for (int s = 0; s < 2; ++s) a64[r][s] += (double)a32[r][s];
    }
  }
  if (act) {
    #pragma unroll
    for (int r = 0; r < 4; ++r) {
      #pragma unroll
      for (int s = 0; s < 2; ++s) {
        int i = it + 25*r, j = j0 + jj + 10*s;
        double v = a64[r][s] * (1.0/999.0);
        if (i == j) v += 1e-4;
        cov[(size_t)b*SPD_*SPD_ + i*SPD_ + j] = (float)v;
      }
    }
  }
}

// ---------------------------------------------------------------------------
// K4b: T1 = C @ W^T
// ---------------------------------------------------------------------------
__global__ __launch_bounds__(256) void k_aff1(const float* __restrict__ cov,
                                              const float* __restrict__ waff,
                                              float* __restrict__ T1) {
  const int b  = blockIdx.x / 5;
  const int j0 = (blockIdx.x % 5) * 20;
  __shared__ float Cs[SPD_*101];
  __shared__ float Ws[20*100];
  for (int idx = threadIdx.x; idx < SPD_*SPD_; idx += 256) {
    int r = idx / 100, c = idx - r*100;
    Cs[r*101 + c] = cov[(size_t)b*SPD_*SPD_ + idx];
  }
  for (int idx = threadIdx.x; idx < 2000; idx += 256) {
    int jl = idx / 100, k = idx - jl*100;
    Ws[idx] = waff[(j0+jl)*100 + k];
  }
  __syncthreads();
  if (threadIdx.x < 250) {
    const int it = threadIdx.x / 10, jj = threadIdx.x % 10;
    double acc[4][2] = {{0.0,0.0},{0.0,0.0},{0.0,0.0},{0.0,0.0}};
    for (int k = 0; k < 100; ++k) {
      double cvv[4], wv[2];
      #pragma unroll
      for (int r = 0; r < 4; ++r) cvv[r] = (double)Cs[(it + 25*r)*101 + k];
      #pragma unroll
      for (int s = 0; s < 2; ++s) wv[s] = (double)Ws[(jj + 10*s)*100 + k];
      #pragma unroll
      for (int r = 0; r < 4; ++r)
        #pragma unroll
        for (int s = 0; s < 2; ++s) acc[r][s] += cvv[r]*wv[s];
    }
    #pragma unroll
    for (int r = 0; r < 4; ++r)
      #pragma unroll
      for (int s = 0; s < 2; ++s)
        T1[(size_t)b*SPD_*SPD_ + (it + 25*r)*100 + (j0 + jj + 10*s)] = (float)acc[r][s];
  }
}

// ---------------------------------------------------------------------------
// K4c: P = W @ T1
// ---------------------------------------------------------------------------
__global__ __launch_bounds__(256) void k_aff2(const float* __restrict__ T1,
                                              const float* __restrict__ waff,
                                              float* __restrict__ P) {
  const int b  = blockIdx.x / 5;
  const int j0 = (blockIdx.x % 5) * 20;
  __shared__ float T1s[100*20];
  for (int idx = threadIdx.x; idx < 2000; idx += 256) {
    int k = idx / 20, jl = idx - k*20;
    T1s[idx] = T1[(size_t)b*SPD_*SPD_ + k*100 + j0 + jl];
  }
  __syncthreads();
  if (threadIdx.x < 250) {
    const int it = threadIdx.x / 10, jj = threadIdx.x % 10;
    double acc[4][2] = {{0.0,0.0},{0.0,0.0},{0.0,0.0},{0.0,0.0}};
    for (int k = 0; k < 100; ++k) {
      double wv[4], tv[2];
      #pragma unroll
      for (int r = 0; r < 4; ++r) wv[r] = (double)waff[(it + 25*r)*100 + k];
      #pragma unroll
      for (int s = 0; s < 2; ++s) tv[s] = (double)T1s[k*20 + jj + 10*s];
      #pragma unroll
      for (int r = 0; r < 4; ++r)
        #pragma unroll
        for (int s = 0; s < 2; ++s) acc[r][s] += wv[r]*tv[s];
    }
    #pragma unroll
    for (int r = 0; r < 4; ++r)
      #pragma unroll
      for (int s = 0; s < 2; ++s)
        P[(size_t)b*SPD_*SPD_ + (it + 25*r)*100 + (j0 + jj + 10*s)] = (float)acc[r][s];
  }
}

// ---------------------------------------------------------------------------
// K5: register-resident systolic one-sided Jacobi (Brent-Luk circle method).
// Round: write pg -> barrier -> read 4 partials -> per-lane decide ->
// fused rotate+send -> BATCHED 50 bpermutes -> selects + next pg.
// Early-exit flag threshold 6.3e-5*sqrt(ab) (>= 5x above fp32 dot noise).
// __launch_bounds__(256,1): let scheduler keep shuffle results in flight.
// ---------------------------------------------------------------------------
__global__ __launch_bounds__(256, 1) void k_eig(const float* __restrict__ P, float* __restrict__ out) {
  __shared__ __align__(16) float G[SPD_*LDSTR];
  __shared__ double wc[SPD_];
  __shared__ __align__(16) float gbuf[2][64*4];
  __shared__ __align__(16) float nbuf[64*8];
  __shared__ int fbuf[4];
  const int tid = threadIdx.x;
  const int b   = blockIdx.x;
  const int w   = tid >> 6;
  const int j   = tid & 63;
  const bool act = (j < 50);
  const int rb  = 25 * w;
  const int srcA = (j == 0)  ? 0  : j-1;
  const int srcB = (j >= 49) ? 49 : j+1;

  float A[25], B[25];
  const float* Pb = P + (size_t)b*SPD_*SPD_;
  #pragma unroll
  for (int i = 0; i < 25; ++i) {
    A[i] = act ? Pb[(rb+i)*SPD_ + j]      : 0.f;
    B[i] = act ? Pb[(rb+i)*SPD_ + (99-j)] : 0.f;
  }
  float pA = 0.f, pB = 0.f;
  #pragma unroll
  for (int i = 0; i < 25; ++i) { pA += A[i]*A[i]; pB += B[i]*B[i]; }
  nbuf[j*8 + w*2 + 0] = pA;
  nbuf[j*8 + w*2 + 1] = pB;
  __syncthreads();
  float nA, nB;
  {
    float4 u0 = *(const float4*)&nbuf[j*8];
    float4 u1 = *(const float4*)&nbuf[j*8+4];
    nA = (u0.x + u0.z) + (u1.x + u1.z);
    nB = (u0.y + u0.w) + (u1.y + u1.w);
  }
  float pg = 0.f;
  #pragma unroll
  for (int i = 0; i < 25; ++i) pg += A[i]*B[i];

  int par = 0;
  for (int sweep = 0; sweep < 14; ++sweep) {
    int swflag = 0;
    for (int r = 0; r < 99; ++r) {
      gbuf[par][j*4 + w] = pg;
      __syncthreads();                       // the ONLY barrier per round
      float4 gp = *(const float4*)&gbuf[par][j*4];
      float gamma = (gp.x + gp.y) + (gp.z + gp.w);

      float cr = 1.f, sr = 0.f;
      float g2 = gamma*gamma;
      float ab = nA*nB;
      // lanes >= 50: pg==0 always -> gamma==0 -> identity (no act guard needed)
      if (g2 > 1e-12f*ab) {                  // rotate if |g| > 1e-6*sqrt(ab)
        if (g2 > 4e-9f*ab) swflag = 1;       // not converged if |g| > 6.3e-5*sqrt(ab)
        float tau = (nB - nA) / (2.f*gamma);
        float t = ((tau >= 0.f) ? 1.f : -1.f) / (fabsf(tau) + sqrtf(1.f + tau*tau));
        cr = rsqrtf(1.f + t*t);
        sr = t*cr;
        nA = nA - t*gamma;
        nB = nB + t*gamma;
      }
      // norm migration
      {
        float sN  = (j == 0) ? nB : nA;
        float rNA = __shfl(sN, srcA, 64);
        float rNB = __shfl(nB, srcB, 64);
        float tA  = (j == 0)  ? nA : rNA;
        float tB  = (j == 49) ? nA : rNB;
        nA = tA; nB = tB;
      }
      // fused rotate + prepare sends
      float na[25], nb[25], sA[25];
      #pragma unroll
      for (int i = 0; i < 25; ++i) {
        na[i] = cr*A[i] - sr*B[i];
        nb[i] = sr*A[i] + cr*B[i];
        sA[i] = (j == 0) ? nb[i] : na[i];
      }
      // batched shuffles (all independent, keep in flight)
      float rA[25], rB[25];
      #pragma unroll
      for (int i = 0; i < 25; ++i) rA[i] = __shfl(sA[i], srcA, 64);
      #pragma unroll
      for (int i = 0; i < 25; ++i) rB[i] = __shfl(nb[i], srcB, 64);
      // selects + next round's partial gamma
      pg = 0.f;
      #pragma unroll
      for (int i = 0; i < 25; ++i) {
        A[i] = (j == 0)  ? na[i] : rA[i];
        B[i] = (j == 49) ? na[i] : rB[i];
        pg += A[i]*B[i];
      }
      par ^= 1;
    }
    // sweep-level convergence check
    unsigned long long any = __ballot(swflag);
    if (j == 0) fbuf[w] = (any != 0ull) ? 1 : 0;
    __syncthreads();
    int f = fbuf[0] | fbuf[1] | fbuf[2] | fbuf[3];
    __syncthreads();
    if (!f) break;
  }

  // dump converged columns to LDS (seat order; order irrelevant for the sum)
  if (act) {
    #pragma unroll
    for (int i = 0; i < 25; ++i) {
      G[j*LDSTR + rb + i]        = A[i];
      G[(50 + j)*LDSTR + rb + i] = B[i];
    }
  }
  __syncthreads();

  // exact fp64 column norms -> wc = log(clip(lam,1e-6)) / lam^2
  if (tid < SPD_) {
    const float* col = &G[tid*LDSTR];
    double s = 0.0;
    for (int i = 0; i < SPD_; ++i) { double v = (double)col[i]; s += v*v; }
    double lam = sqrt(s);
    double lc  = (lam < 1e-6) ? 1e-6 : lam;
    wc[tid] = log(lc) / ((s > 1e-300) ? s : 1e-300);
  }
  __syncthreads();

  // L = sum_c wc[c] * g_c g_c^T ; scaled upper-tri -> out[64 + b*5050 + idx]
  for (int tile = tid; tile < 625; tile += 256) {
    const int ti = (tile / 25) * 4;
    const int tj = (tile % 25) * 4;
    float acc[4][4];
    #pragma unroll
    for (int r = 0; r < 4; ++r)
      #pragma unroll
      for (int s = 0; s < 4; ++s) acc[r][s] = 0.f;
    for (int c = 0; c < SPD_; ++c) {
      const float* col = &G[c*LDSTR];
      float4 ga = *(const float4*)&col[ti];
      float4 gb = *(const float4*)&col[tj];
      float wcv = (float)wc[c];
      float wa[4] = { wcv*ga.x, wcv*ga.y, wcv*ga.z, wcv*ga.w };
      float bv[4] = { gb.x, gb.y, gb.z, gb.w };
      #pragma unroll
      for (int r = 0; r < 4; ++r)
        #pragma unroll
        for (int s = 0; s < 4; ++s) acc[r][s] += wa[r]*bv[s];
    }
    const float RT2 = 1.41421356237309505f;
    #pragma unroll
    for (int r = 0; r < 4; ++r) {
      #pragma unroll
      for (int s = 0; s < 4; ++s) {
        int i = ti + r, jx = tj + s;
        if (i <= jx) {
          int idx = i*SPD_ - (i*(i+1))/2 + jx;
          out[64 + b*5050 + idx] = acc[r][s] * (i == jx ? 1.f : RT2);
        }
      }
    }
  }
}

// ---------------------------------------------------------------------------
// K6: logits = flat @ w_fc^T + b_fc
// ---------------------------------------------------------------------------
__global__ __launch_bounds__(256) void k_fc(const float* __restrict__ wfc,
                                            const float* __restrict__ bfc,
                                            float* __restrict__ out) {
  __shared__ float red[8];
  const int b = blockIdx.x;
  const float* flat = out + 64 + b*5050;
  float a0 = 0.f, a1 = 0.f, a2 = 0.f, a3 = 0.f;
  for (int k = threadIdx.x; k < 5050; k += 256) {
    float f = flat[k];
    a0 += f * wfc[k];
    a1 += f * wfc[5050 + k];
    a2 += f * wfc[10100 + k];
    a3 += f * wfc[15150 + k];
  }
  a0 = block_sum(a0, red);
  a1 = block_sum(a1, red);
  a2 = block_sum(a2, red);
  a3 = block_sum(a3, red);
  if (threadIdx.x == 0) {
    out[b*4 + 0] = a0 + bfc[0];
    out[b*4 + 1] = a1 + bfc[1];
    out[b*4 + 2] = a2 + bfc[2];
    out[b*4 + 3] = a3 + bfc[3];
  }
}

extern "C" void kernel_launch(void* const* d_in, const int* in_sizes, int n_in,
                              void* d_out, int out_size, void* d_ws, size_t ws_size,
                              hipStream_t stream) {
  (void)in_sizes; (void)n_in; (void)out_size; (void)ws_size;
  const float* x = (const float*)d_in[0];
  const float* bw[3][9];
  for (int i = 0; i < 3; ++i)
    for (int jx = 0; jx < 9; ++jx)
      bw[i][jx] = (const float*)d_in[1 + i*9 + jx];
  const float* w_sconv = (const float*)d_in[28];
  const float* w_aff   = (const float*)d_in[29];
  const float* w_fc    = (const float*)d_in[30];
  const float* b_fc    = (const float*)d_in[31];

  char* ws = (char*)d_ws;
  float* M2   = (float*)(ws + OFF_M2);
  float* hcat = (float*)(ws + OFF_HCAT);
  float* xc   = (float*)(ws + OFF_XC);
  float* cov  = (float*)(ws + OFF_COV);
  float* T1   = (float*)(ws + OFF_T1);
  float* P    = (float*)(ws + OFF_P);
  float* out  = (float*)d_out;

  PrepPtrs pp; FrontPtrs fp;
  for (int i = 0; i < 3; ++i) {
    pp.w1[i] = bw[i][0]; pp.w2[i] = bw[i][1]; pp.w3[i] = bw[i][2]; pp.w4[i] = bw[i][3];
    fp.g1[i] = bw[i][4]; fp.b1[i] = bw[i][5]; fp.w5[i] = bw[i][6];
    fp.g2[i] = bw[i][7]; fp.b2[i] = bw[i][8];
  }
  fp.K[0] = 15; fp.K[1] = 75; fp.K[2] = 55;

  hipLaunchKernelGGL(k_prep,  dim3(3),            dim3(256), 0, stream, pp, M2);
  hipLaunchKernelGGL(k_front, dim3(3*B_*FCH_),    dim3(256), 0, stream, x, M2, fp, hcat);
  hipLaunchKernelGGL(k_sconv, dim3(B_*10),        dim3(256), 0, stream, hcat, w_sconv, xc);
  hipLaunchKernelGGL(k_cov,   dim3(B_*5),         dim3(256), 0, stream, xc, cov);
  hipLaunchKernelGGL(k_aff1,  dim3(B_*5),         dim3(256), 0, stream, cov, w_aff, T1);
  hipLaunchKernelGGL(k_aff2,  dim3(B_*5),         dim3(256), 0, stream, T1, w_aff, P);
  hipLaunchKernelGGL(k_eig,   dim3(B_),           dim3(256), 0, stream, P, out);
  hipLaunchKernelGGL(k_fc,    dim3(B_),           dim3(256), 0, stream, w_fc, b_fc, out);
}

// Round 5
// 1467.891 us; speedup vs baseline: 1.5785x; 1.5785x over previous
//
#include <hip/hip_runtime.h>

#define B_ 16
#define CN_ 22
#define T_ 1000
#define EXP_ 300
#define FCH_ 150
#define SPD_ 100
#define LDSTR 108
#define MAXSWEEP 10

// workspace layout (bytes)
static constexpr unsigned long long OFF_M2   = 0ull;
static constexpr unsigned long long OFF_HCAT = 65536ull;
static constexpr unsigned long long OFF_XC   = OFF_HCAT + 28800000ull;
static constexpr unsigned long long OFF_COV  = OFF_XC   + 6400000ull;
static constexpr unsigned long long OFF_T1   = OFF_COV  + 640000ull;
static constexpr unsigned long long OFF_P    = OFF_T1   + 640000ull;
// G / wc reuse the xc region (dead after k_cov): 16*10000 f32 + 16*100 f64
static constexpr unsigned long long OFF_G    = OFF_XC;
static constexpr unsigned long long OFF_WC   = OFF_XC + 640000ull;

struct PrepPtrs  { const float* w1[3]; const float* w2[3]; const float* w3[3]; const float* w4[3]; };
struct FrontPtrs { const float* g1[3]; const float* b1[3]; const float* w5[3];
                   const float* g2[3]; const float* b2[3]; int K[3]; };

__device__ __forceinline__ float block_sum(float v, float* sbuf) {
  #pragma unroll
  for (int off = 32; off > 0; off >>= 1) v += __shfl_down(v, off, 64);
  const int wid  = threadIdx.x >> 6;
  const int lane = threadIdx.x & 63;
  const int nw   = blockDim.x >> 6;
  if (lane == 0) sbuf[wid] = v;
  __syncthreads();
  float r = 0.f;
  for (int w = 0; w < nw; ++w) r += sbuf[w];
  __syncthreads();
  return r;
}

// DPP wave shifts: SHR1 -> dst[i]=src[i-1] (lane0 takes `old`);
//                  SHL1 -> dst[i]=src[i+1] (lane63 takes `old`).
__device__ __forceinline__ float dpp_shr1(float old_, float src) {
  return __builtin_bit_cast(float, __builtin_amdgcn_update_dpp(
      __builtin_bit_cast(int, old_), __builtin_bit_cast(int, src),
      0x138, 0xf, 0xf, false));
}
__device__ __forceinline__ float dpp_shl1(float old_, float src) {
  return __builtin_bit_cast(float, __builtin_amdgcn_update_dpp(
      __builtin_bit_cast(int, old_), __builtin_bit_cast(int, src),
      0x130, 0xf, 0xf, false));
}

// ---------------------------------------------------------------------------
// K1: fold conv(3,1) + w2-expand + max-norm depthwise spatial + pointwise
// ---------------------------------------------------------------------------
__global__ __launch_bounds__(256) void k_prep(PrepPtrs pp, float* __restrict__ M2) {
  const int beta = blockIdx.x;
  __shared__ float w3r[EXP_*CN_];
  __shared__ float M[FCH_*CN_];
  const float* w1 = pp.w1[beta];
  const float* w2 = pp.w2[beta];
  const float* w3 = pp.w3[beta];
  const float* w4 = pp.w4[beta];

  for (int g = threadIdx.x; g < EXP_; g += 256) {
    float s = 0.f;
    for (int c = 0; c < CN_; ++c) { float w = w3[g*CN_ + c]; s += w*w; }
    float n = sqrtf(s);
    float scale = fminf(1.f, 1.f/(n + 1e-12f)) * w2[g];
    for (int c = 0; c < CN_; ++c) w3r[g*CN_ + c] = w3[g*CN_ + c] * scale;
  }
  __syncthreads();
  for (int idx = threadIdx.x; idx < FCH_*CN_; idx += 256) {
    int o = idx / CN_, c = idx - o*CN_;
    float acc = 0.f;
    for (int g = 0; g < EXP_; ++g) acc += w4[o*EXP_ + g] * w3r[g*CN_ + c];
    M[idx] = acc;
  }
  __syncthreads();
  const float k0 = w1[0], k1 = w1[1], k2 = w1[2];
  for (int idx = threadIdx.x; idx < FCH_*CN_; idx += 256) {
    int c = idx % CN_;
    float v = k1 * M[idx];
    if (c > 0)       v += k2 * M[idx - 1];
    if (c < CN_ - 1) v += k0 * M[idx + 1];
    M2[beta*FCH_*CN_ + idx] = v;
  }
}

// ---------------------------------------------------------------------------
// K2: per (beta,b,o) row: h = M2 row @ x[b] -> LN -> depthwise conv K -> LN
// ---------------------------------------------------------------------------
__global__ __launch_bounds__(256) void k_front(const float* __restrict__ x,
                                               const float* __restrict__ M2,
                                               FrontPtrs fp,
                                               float* __restrict__ hcat) {
  const int wg   = blockIdx.x;
  const int beta = wg / (B_*FCH_);
  const int rem  = wg - beta*(B_*FCH_);
  const int b    = rem / FCH_;
  const int o    = rem - b*FCH_;
  const int K    = fp.K[beta];
  const int Kh   = K >> 1;

  __shared__ float m2[CN_];
  __shared__ float hb2[T_];
  __shared__ float w5s[80];
  __shared__ float red[8];

  if (threadIdx.x < CN_) m2[threadIdx.x] = M2[(beta*FCH_ + o)*CN_ + threadIdx.x];
  if (threadIdx.x < K)   w5s[threadIdx.x] = fp.w5[beta][o*K + threadIdx.x];
  __syncthreads();

  const float* xb = x + (size_t)b*CN_*T_;
  float hv[4];
  float psum = 0.f;
  #pragma unroll
  for (int e = 0; e < 4; ++e) {
    int t = threadIdx.x + 256*e;
    float acc = 0.f;
    if (t < T_) {
      #pragma unroll
      for (int c = 0; c < CN_; ++c) acc += m2[c] * xb[c*T_ + t];
    }
    hv[e] = acc; psum += acc;
  }
  float mean = block_sum(psum, red) * (1.f/T_);
  float pv = 0.f;
  #pragma unroll
  for (int e = 0; e < 4; ++e) { int t = threadIdx.x + 256*e; if (t < T_) { float d = hv[e]-mean; pv += d*d; } }
  float var = block_sum(pv, red) * (1.f/T_);
  float inv = rsqrtf(var + 1e-5f);
  const float* g1 = fp.g1[beta]; const float* b1 = fp.b1[beta];
  #pragma unroll
  for (int e = 0; e < 4; ++e) { int t = threadIdx.x + 256*e; if (t < T_) hb2[t] = (hv[e]-mean)*inv*g1[t] + b1[t]; }
  __syncthreads();

  float cv[4];
  float ps2 = 0.f;
  #pragma unroll
  for (int e = 0; e < 4; ++e) {
    int t = threadIdx.x + 256*e;
    float acc = 0.f;
    if (t < T_) {
      int lo = t - Kh;
      for (int k = 0; k < K; ++k) {
        int tt = lo + k;
        float hvv = (tt >= 0 && tt < T_) ? hb2[tt] : 0.f;
        acc += hvv * w5s[k];
      }
    }
    cv[e] = acc; ps2 += acc;
  }
  float mean2 = block_sum(ps2, red) * (1.f/T_);
  float pv2 = 0.f;
  #pragma unroll
  for (int e = 0; e < 4; ++e) { int t = threadIdx.x + 256*e; if (t < T_) { float d = cv[e]-mean2; pv2 += d*d; } }
  float var2 = block_sum(pv2, red) * (1.f/T_);
  float inv2 = rsqrtf(var2 + 1e-5f);
  const float* g2 = fp.g2[beta]; const float* b2 = fp.b2[beta];
  float* hrow = hcat + ((size_t)b*(3*FCH_) + beta*FCH_ + o)*T_;
  #pragma unroll
  for (int e = 0; e < 4; ++e) { int t = threadIdx.x + 256*e; if (t < T_) hrow[t] = (cv[e]-mean2)*inv2*g2[t] + b2[t]; }
}

// ---------------------------------------------------------------------------
// K3: h_s = w_sconv @ hcat per b, subtract per-row time mean, store xc.
// ---------------------------------------------------------------------------
__global__ __launch_bounds__(256) void k_sconv(const float* __restrict__ hcat,
                                               const float* __restrict__ wsc,
                                               float* __restrict__ xc) {
  const int b  = blockIdx.x / 10;
  const int s0 = (blockIdx.x % 10) * 10;
  __shared__ float ws[10*450];
  __shared__ float red[8];
  for (int idx = threadIdx.x; idx < 4500; idx += 256) {
    int s = idx / 450, i = idx - s*450;
    ws[idx] = wsc[(s0+s)*450 + i];
  }
  __syncthreads();
  float acc[10][4];
  #pragma unroll
  for (int s = 0; s < 10; ++s)
    #pragma unroll
    for (int e = 0; e < 4; ++e) acc[s][e] = 0.f;
  const float* hb = hcat + (size_t)b*450*T_;
  for (int i = 0; i < 450; ++i) {
    float xv[4];
    #pragma unroll
    for (int e = 0; e < 4; ++e) { int t = threadIdx.x + 256*e; xv[e] = (t < T_) ? hb[(size_t)i*T_ + t] : 0.f; }
    #pragma unroll
    for (int s = 0; s < 10; ++s) {
      float w = ws[s*450 + i];
      #pragma unroll
      for (int e = 0; e < 4; ++e) acc[s][e] += w * xv[e];
    }
  }
  for (int s = 0; s < 10; ++s) {
    float mu = block_sum(acc[s][0]+acc[s][1]+acc[s][2]+acc[s][3], red) * (1.f/T_);
    float* xr = xc + ((size_t)b*SPD_ + s0 + s)*T_;
    #pragma unroll
    for (int e = 0; e < 4; ++e) { int t = threadIdx.x + 256*e; if (t < T_) xr[t] = acc[s][e] - mu; }
  }
}

// ---------------------------------------------------------------------------
// K4a: cov = xc xc^T /999 + 1e-4 I
// ---------------------------------------------------------------------------
__global__ __launch_bounds__(256) void k_cov(const float* __restrict__ xc, float* __restrict__ cov) {
  const int b  = blockIdx.x / 5;
  const int j0 = (blockIdx.x % 5) * 20;
  __shared__ __align__(16) float xst[SPD_*100];
  const int it = threadIdx.x / 10;
  const int jj = threadIdx.x - it*10;
  const bool act = threadIdx.x < 250;
  double a64[4][2] = {{0.0,0.0},{0.0,0.0},{0.0,0.0},{0.0,0.0}};
  for (int ch = 0; ch < 10; ++ch) {
    __syncthreads();
    const int tc0 = ch*100;
    for (int idx = threadIdx.x; idx < SPD_*100; idx += 256) {
      int row = idx / 100, tt = idx - row*100;
      xst[idx] = xc[((size_t)b*SPD_ + row)*T_ + tc0 + tt];
    }
    __syncthreads();
    if (act) {
      float a32[4][2] = {{0,0},{0,0},{0,0},{0,0}};
      for (int t4 = 0; t4 < 100; t4 += 4) {
        float4 xi[4], xj[2];
        #pragma unroll
        for (int r = 0; r < 4; ++r) xi[r] = *(const float4*)&xst[(it + 25*r)*100 + t4];
        #pragma unroll
        for (int s = 0; s < 2; ++s) xj[s] = *(const float4*)&xst[(j0 + jj + 10*s)*100 + t4];
        #pragma unroll
        for (int r = 0; r < 4; ++r)
          #pragma unroll
          for (int s = 0; s < 2; ++s)
            a32[r][s] += xi[r].x*xj[s].x + xi[r].y*xj[s].y + xi[r].z*xj[s].z + xi[r].w*xj[s].w;
      }
      #pragma unroll
      for (int r = 0; r < 4; ++r)
        #pragma unroll
        for (int s = 0; s < 2; ++s) a64[r][s] += (double)a32[r][s];
    }
  }
  if (act) {
    #pragma unroll
    for (int r = 0; r < 4; ++r) {
      #pragma unroll
      for (int s = 0; s < 2; ++s) {
        int i = it + 25*r, j = j0 + jj + 10*s;
        double v = a64[r][s] * (1.0/999.0);
        if (i == j) v += 1e-4;
        cov[(size_t)b*SPD_*SPD_ + i*SPD_ + j] = (float)v;
      }
    }
  }
}

// ---------------------------------------------------------------------------
// K4b: T1 = C @ W^T
// ---------------------------------------------------------------------------
__global__ __launch_bounds__(256) void k_aff1(const float* __restrict__ cov,
                                              const float* __restrict__ waff,
                                              float* __restrict__ T1) {
  const int b  = blockIdx.x / 5;
  const int j0 = (blockIdx.x % 5) * 20;
  __shared__ float Cs[SPD_*101];
  __shared__ float Ws[20*100];
  for (int idx = threadIdx.x; idx < SPD_*SPD_; idx += 256) {
    int r = idx / 100, c = idx - r*100;
    Cs[r*101 + c] = cov[(size_t)b*SPD_*SPD_ + idx];
  }
  for (int idx = threadIdx.x; idx < 2000; idx += 256) {
    int jl = idx / 100, k = idx - jl*100;
    Ws[idx] = waff[(j0+jl)*100 + k];
  }
  __syncthreads();
  if (threadIdx.x < 250) {
    const int it = threadIdx.x / 10, jj = threadIdx.x % 10;
    double acc[4][2] = {{0.0,0.0},{0.0,0.0},{0.0,0.0},{0.0,0.0}};
    for (int k = 0; k < 100; ++k) {
      double cvv[4], wv[2];
      #pragma unroll
      for (int r = 0; r < 4; ++r) cvv[r] = (double)Cs[(it + 25*r)*101 + k];
      #pragma unroll
      for (int s = 0; s < 2; ++s) wv[s] = (double)Ws[(jj + 10*s)*100 + k];
      #pragma unroll
      for (int r = 0; r < 4; ++r)
        #pragma unroll
        for (int s = 0; s < 2; ++s) acc[r][s] += cvv[r]*wv[s];
    }
    #pragma unroll
    for (int r = 0; r < 4; ++r)
      #pragma unroll
      for (int s = 0; s < 2; ++s)
        T1[(size_t)b*SPD_*SPD_ + (it + 25*r)*100 + (j0 + jj + 10*s)] = (float)acc[r][s];
  }
}

// ---------------------------------------------------------------------------
// K4c: P = W @ T1
// ---------------------------------------------------------------------------
__global__ __launch_bounds__(256) void k_aff2(const float* __restrict__ T1,
                                              const float* __restrict__ waff,
                                              float* __restrict__ P) {
  const int b  = blockIdx.x / 5;
  const int j0 = (blockIdx.x % 5) * 20;
  __shared__ float T1s[100*20];
  for (int idx = threadIdx.x; idx < 2000; idx += 256) {
    int k = idx / 20, jl = idx - k*20;
    T1s[idx] = T1[(size_t)b*SPD_*SPD_ + k*100 + j0 + jl];
  }
  __syncthreads();
  if (threadIdx.x < 250) {
    const int it = threadIdx.x / 10, jj = threadIdx.x % 10;
    double acc[4][2] = {{0.0,0.0},{0.0,0.0},{0.0,0.0},{0.0,0.0}};
    for (int k = 0; k < 100; ++k) {
      double wv[4], tv[2];
      #pragma unroll
      for (int r = 0; r < 4; ++r) wv[r] = (double)waff[(it + 25*r)*100 + k];
      #pragma unroll
      for (int s = 0; s < 2; ++s) tv[s] = (double)T1s[k*20 + jj + 10*s];
      #pragma unroll
      for (int r = 0; r < 4; ++r)
        #pragma unroll
        for (int s = 0; s < 2; ++s) acc[r][s] += wv[r]*tv[s];
    }
    #pragma unroll
    for (int r = 0; r < 4; ++r)
      #pragma unroll
      for (int s = 0; s < 2; ++s)
        P[(size_t)b*SPD_*SPD_ + (it + 25*r)*100 + (j0 + jj + 10*s)] = (float)acc[r][s];
  }
}

// ---------------------------------------------------------------------------
// K5: register-resident systolic one-sided Jacobi, DPP migration (no DS pipe
// in the migration), act-gated early exit at |gamma| > 1e-4*sqrt(ab).
// Writes converged columns G + log-weights wc to workspace for k_lout.
// ---------------------------------------------------------------------------
__global__ __launch_bounds__(256, 1) void k_eig(const float* __restrict__ P,
                                                float* __restrict__ Gout,
                                                double* __restrict__ WCout) {
  __shared__ __align__(16) float G[SPD_*LDSTR];
  __shared__ __align__(16) float gbuf[2][64*4];
  __shared__ __align__(16) float nbuf[64*8];
  __shared__ int fbuf[4];
  const int tid = threadIdx.x;
  const int b   = blockIdx.x;
  const int w   = tid >> 6;
  const int j   = tid & 63;
  const bool act = (j < 50);
  const int rb  = 25 * w;

  float A[25], B[25];
  const float* Pb = P + (size_t)b*SPD_*SPD_;
  #pragma unroll
  for (int i = 0; i < 25; ++i) {
    A[i] = act ? Pb[(rb+i)*SPD_ + j]      : 0.f;
    B[i] = act ? Pb[(rb+i)*SPD_ + (99-j)] : 0.f;
  }
  float pA = 0.f, pB = 0.f;
  #pragma unroll
  for (int i = 0; i < 25; ++i) { pA += A[i]*A[i]; pB += B[i]*B[i]; }
  nbuf[j*8 + w*2 + 0] = pA;
  nbuf[j*8 + w*2 + 1] = pB;
  __syncthreads();
  float nA, nB;
  {
    float4 u0 = *(const float4*)&nbuf[j*8];
    float4 u1 = *(const float4*)&nbuf[j*8+4];
    nA = (u0.x + u0.z) + (u1.x + u1.z);
    nB = (u0.y + u0.w) + (u1.y + u1.w);
  }
  float pg = 0.f;
  #pragma unroll
  for (int i = 0; i < 25; ++i) pg += A[i]*B[i];

  int par = 0;
  for (int sweep = 0; sweep < MAXSWEEP; ++sweep) {
    int swflag = 0;
    for (int r = 0; r < 99; ++r) {
      gbuf[par][j*4 + w] = pg;
      __syncthreads();                       // the ONLY barrier per round
      float4 gp = *(const float4*)&gbuf[par][j*4];
      float gamma = (gp.x + gp.y) + (gp.z + gp.w);

      float cr = 1.f, sr = 0.f;
      float g2 = gamma*gamma;
      float ab = nA*nB;
      if (act && g2 > 1e-12f*ab) {           // rotate if |g| > 1e-6*sqrt(ab)
        if (g2 > 1e-8f*ab) swflag = 1;       // continue if |g| > 1e-4*sqrt(ab)
        float tau = (nB - nA) / (2.f*gamma);
        float t = ((tau >= 0.f) ? 1.f : -1.f) / (fabsf(tau) + sqrtf(1.f + tau*tau));
        cr = rsqrtf(1.f + t*t);
        sr = t*cr;
        nA = nA - t*gamma;
        nB = nB + t*gamma;
      }
      // norm migration (DPP): nA'[j] = (j==0)? nA : sendN[j-1]; nB'[j] = (j==49)? nA_old : nB[j+1]
      {
        float sendN = (j == 0) ? nB : nA;
        float rNA = dpp_shr1(nA, sendN);     // lane0 keeps old nA
        float rNB = dpp_shl1(nB, nB);        // lane63 keeps old (garbage ok)
        float newB = (j == 49) ? nA : rNB;
        nA = rNA; nB = newB;
      }
      // fused rotate + DPP migrate + next-round partial gamma
      pg = 0.f;
      #pragma unroll
      for (int i = 0; i < 25; ++i) {
        float na = cr*A[i] - sr*B[i];
        float nb = sr*A[i] + cr*B[i];
        float sendA = (j == 0) ? nb : na;
        float rA = dpp_shr1(na, sendA);      // lane0 keeps na
        float rB = dpp_shl1(nb, nb);         // lane63 keeps old (garbage ok)
        A[i] = rA;
        B[i] = (j == 49) ? na : rB;
        pg += A[i]*B[i];
      }
      par ^= 1;
    }
    unsigned long long any = __ballot(swflag);
    if (j == 0) fbuf[w] = (any != 0ull) ? 1 : 0;
    __syncthreads();
    int f = fbuf[0] | fbuf[1] | fbuf[2] | fbuf[3];
    __syncthreads();
    if (!f) break;
  }

  // dump converged columns to LDS (seat order; order irrelevant for the sum)
  if (act) {
    #pragma unroll
    for (int i = 0; i < 25; ++i) {
      G[j*LDSTR + rb + i]        = A[i];
      G[(50 + j)*LDSTR + rb + i] = B[i];
    }
  }
  __syncthreads();

  // exact fp64 column norms -> wc = log(clip(lam,1e-6)) / lam^2 ; write out
  if (tid < SPD_) {
    const float* col = &G[tid*LDSTR];
    double s = 0.0;
    for (int i = 0; i < SPD_; ++i) { double v = (double)col[i]; s += v*v; }
    double lam = sqrt(s);
    double lc  = (lam < 1e-6) ? 1e-6 : lam;
    WCout[b*SPD_ + tid] = log(lc) / ((s > 1e-300) ? s : 1e-300);
  }
  // coalesced dump of G to workspace (col-major, stride 100)
  for (int idx = tid; idx < SPD_*SPD_; idx += 256) {
    int c = idx / SPD_, i = idx - c*SPD_;
    Gout[(size_t)b*SPD_*SPD_ + idx] = G[c*LDSTR + i];
  }
}

// ---------------------------------------------------------------------------
// K5b: L = sum_c wc[c] * g_c g_c^T ; scaled upper-tri -> out[64 + b*5050 + idx]
// ---------------------------------------------------------------------------
__global__ __launch_bounds__(256) void k_lout(const float* __restrict__ Gin,
                                              const double* __restrict__ WCin,
                                              float* __restrict__ out) {
  __shared__ __align__(16) float G[SPD_*SPD_];
  __shared__ float wcs[SPD_];
  const int tid = threadIdx.x;
  const int b   = blockIdx.x;
  for (int idx = tid; idx < SPD_*SPD_; idx += 256)
    G[idx] = Gin[(size_t)b*SPD_*SPD_ + idx];
  if (tid < SPD_) wcs[tid] = (float)WCin[b*SPD_ + tid];
  __syncthreads();

  for (int tile = tid; tile < 625; tile += 256) {
    const int ti = (tile / 25) * 4;
    const int tj = (tile % 25) * 4;
    float acc[4][4];
    #pragma unroll
    for (int r = 0; r < 4; ++r)
      #pragma unroll
      for (int s = 0; s < 4; ++s) acc[r][s] = 0.f;
    for (int c = 0; c < SPD_; ++c) {
      const float* col = &G[c*SPD_];
      float4 ga = *(const float4*)&col[ti];
      float4 gb = *(const float4*)&col[tj];
      float wcv = wcs[c];
      float wa[4] = { wcv*ga.x, wcv*ga.y, wcv*ga.z, wcv*ga.w };
      float bv[4] = { gb.x, gb.y, gb.z, gb.w };
      #pragma unroll
      for (int r = 0; r < 4; ++r)
        #pragma unroll
        for (int s = 0; s < 4; ++s) acc[r][s] += wa[r]*bv[s];
    }
    const float RT2 = 1.41421356237309505f;
    #pragma unroll
    for (int r = 0; r < 4; ++r) {
      #pragma unroll
      for (int s = 0; s < 4; ++s) {
        int i = ti + r, jx = tj + s;
        if (i <= jx) {
          int idx = i*SPD_ - (i*(i+1))/2 + jx;
          out[64 + b*5050 + idx] = acc[r][s] * (i == jx ? 1.f : RT2);
        }
      }
    }
  }
}

// ---------------------------------------------------------------------------
// K6: logits = flat @ w_fc^T + b_fc
// ---------------------------------------------------------------------------
__global__ __launch_bounds__(256) void k_fc(const float* __restrict__ wfc,
                                            const float* __restrict__ bfc,
                                            float* __restrict__ out) {
  __shared__ float red[8];
  const int b = blockIdx.x;
  const float* flat = out + 64 + b*5050;
  float a0 = 0.f, a1 = 0.f, a2 = 0.f, a3 = 0.f;
  for (int k = threadIdx.x; k < 5050; k += 256) {
    float f = flat[k];
    a0 += f * wfc[k];
    a1 += f * wfc[5050 + k];
    a2 += f * wfc[10100 + k];
    a3 += f * wfc[15150 + k];
  }
  a0 = block_sum(a0, red);
  a1 = block_sum(a1, red);
  a2 = block_sum(a2, red);
  a3 = block_sum(a3, red);
  if (threadIdx.x == 0) {
    out[b*4 + 0] = a0 + bfc[0];
    out[b*4 + 1] = a1 + bfc[1];
    out[b*4 + 2] = a2 + bfc[2];
    out[b*4 + 3] = a3 + bfc[3];
  }
}

extern "C" void kernel_launch(void* const* d_in, const int* in_sizes, int n_in,
                              void* d_out, int out_size, void* d_ws, size_t ws_size,
                              hipStream_t stream) {
  (void)in_sizes; (void)n_in; (void)out_size; (void)ws_size;
  const float* x = (const float*)d_in[0];
  const float* bw[3][9];
  for (int i = 0; i < 3; ++i)
    for (int jx = 0; jx < 9; ++jx)
      bw[i][jx] = (const float*)d_in[1 + i*9 + jx];
  const float* w_sconv = (const float*)d_in[28];
  const float* w_aff   = (const float*)d_in[29];
  const float* w_fc    = (const float*)d_in[30];
  const float* b_fc    = (const float*)d_in[31];

  char* ws = (char*)d_ws;
  float*  M2   = (float*)(ws + OFF_M2);
  float*  hcat = (float*)(ws + OFF_HCAT);
  float*  xc   = (float*)(ws + OFF_XC);
  float*  cov  = (float*)(ws + OFF_COV);
  float*  T1   = (float*)(ws + OFF_T1);
  float*  P    = (float*)(ws + OFF_P);
  float*  G    = (float*)(ws + OFF_G);    // reuses xc region (dead after k_cov)
  double* WC   = (double*)(ws + OFF_WC);
  float*  out  = (float*)d_out;

  PrepPtrs pp; FrontPtrs fp;
  for (int i = 0; i < 3; ++i) {
    pp.w1[i] = bw[i][0]; pp.w2[i] = bw[i][1]; pp.w3[i] = bw[i][2]; pp.w4[i] = bw[i][3];
    fp.g1[i] = bw[i][4]; fp.b1[i] = bw[i][5]; fp.w5[i] = bw[i][6];
    fp.g2[i] = bw[i][7]; fp.b2[i] = bw[i][8];
  }
  fp.K[0] = 15; fp.K[1] = 75; fp.K[2] = 55;

  hipLaunchKernelGGL(k_prep,  dim3(3),            dim3(256), 0, stream, pp, M2);
  hipLaunchKernelGGL(k_front, dim3(3*B_*FCH_),    dim3(256), 0, stream, x, M2, fp, hcat);
  hipLaunchKernelGGL(k_sconv, dim3(B_*10),        dim3(256), 0, stream, hcat, w_sconv, xc);
  hipLaunchKernelGGL(k_cov,   dim3(B_*5),         dim3(256), 0, stream, xc, cov);
  hipLaunchKernelGGL(k_aff1,  dim3(B_*5),         dim3(256), 0, stream, cov, w_aff, T1);
  hipLaunchKernelGGL(k_aff2,  dim3(B_*5),         dim3(256), 0, stream, T1, w_aff, P);
  hipLaunchKernelGGL(k_eig,   dim3(B_),           dim3(256), 0, stream, P, G, WC);
  hipLaunchKernelGGL(k_lout,  dim3(B_),           dim3(256), 0, stream, G, WC, out);
  hipLaunchKernelGGL(k_fc,    dim3(B_),           dim3(256), 0, stream, w_fc, b_fc, out);
}

// Round 6
// 1296.772 us; speedup vs baseline: 1.7868x; 1.1320x over previous
//
#include <hip/hip_runtime.h>

#define B_ 16
#define CN_ 22
#define T_ 1000
#define EXP_ 300
#define FCH_ 150
#define SPD_ 100
#define LDSTR 108
#define MAXSWEEP 8

// workspace layout (bytes)
static constexpr unsigned long long OFF_M2   = 0ull;
static constexpr unsigned long long OFF_HCAT = 65536ull;
static constexpr unsigned long long OFF_XC   = OFF_HCAT + 28800000ull;
static constexpr unsigned long long OFF_COV  = OFF_XC   + 6400000ull;
static constexpr unsigned long long OFF_T1   = OFF_COV  + 640000ull;
static constexpr unsigned long long OFF_P    = OFF_T1   + 640000ull;
// G / wc reuse the xc region (dead after k_cov): 16*10000 f32 + 16*100 f64
static constexpr unsigned long long OFF_G    = OFF_XC;
static constexpr unsigned long long OFF_WC   = OFF_XC + 640000ull;

struct PrepPtrs  { const float* w1[3]; const float* w2[3]; const float* w3[3]; const float* w4[3]; };
struct FrontPtrs { const float* g1[3]; const float* b1[3]; const float* w5[3];
                   const float* g2[3]; const float* b2[3]; int K[3]; };

__device__ __forceinline__ float block_sum(float v, float* sbuf) {
  #pragma unroll
  for (int off = 32; off > 0; off >>= 1) v += __shfl_down(v, off, 64);
  const int wid  = threadIdx.x >> 6;
  const int lane = threadIdx.x & 63;
  const int nw   = blockDim.x >> 6;
  if (lane == 0) sbuf[wid] = v;
  __syncthreads();
  float r = 0.f;
  for (int w = 0; w < nw; ++w) r += sbuf[w];
  __syncthreads();
  return r;
}

// DPP wave shifts: SHR1 -> dst[i]=src[i-1] (lane0 takes `old`);
//                  SHL1 -> dst[i]=src[i+1] (lane63 takes `old`).
__device__ __forceinline__ float dpp_shr1(float old_, float src) {
  return __builtin_bit_cast(float, __builtin_amdgcn_update_dpp(
      __builtin_bit_cast(int, old_), __builtin_bit_cast(int, src),
      0x138, 0xf, 0xf, false));
}
__device__ __forceinline__ float dpp_shl1(float old_, float src) {
  return __builtin_bit_cast(float, __builtin_amdgcn_update_dpp(
      __builtin_bit_cast(int, old_), __builtin_bit_cast(int, src),
      0x130, 0xf, 0xf, false));
}

// ---------------------------------------------------------------------------
// K1: fold conv(3,1) + w2-expand + max-norm depthwise spatial + pointwise
// ---------------------------------------------------------------------------
__global__ __launch_bounds__(256) void k_prep(PrepPtrs pp, float* __restrict__ M2) {
  const int beta = blockIdx.x;
  __shared__ float w3r[EXP_*CN_];
  __shared__ float M[FCH_*CN_];
  const float* w1 = pp.w1[beta];
  const float* w2 = pp.w2[beta];
  const float* w3 = pp.w3[beta];
  const float* w4 = pp.w4[beta];

  for (int g = threadIdx.x; g < EXP_; g += 256) {
    float s = 0.f;
    for (int c = 0; c < CN_; ++c) { float w = w3[g*CN_ + c]; s += w*w; }
    float n = sqrtf(s);
    float scale = fminf(1.f, 1.f/(n + 1e-12f)) * w2[g];
    for (int c = 0; c < CN_; ++c) w3r[g*CN_ + c] = w3[g*CN_ + c] * scale;
  }
  __syncthreads();
  for (int idx = threadIdx.x; idx < FCH_*CN_; idx += 256) {
    int o = idx / CN_, c = idx - o*CN_;
    float acc = 0.f;
    for (int g = 0; g < EXP_; ++g) acc += w4[o*EXP_ + g] * w3r[g*CN_ + c];
    M[idx] = acc;
  }
  __syncthreads();
  const float k0 = w1[0], k1 = w1[1], k2 = w1[2];
  for (int idx = threadIdx.x; idx < FCH_*CN_; idx += 256) {
    int c = idx % CN_;
    float v = k1 * M[idx];
    if (c > 0)       v += k2 * M[idx - 1];
    if (c < CN_ - 1) v += k0 * M[idx + 1];
    M2[beta*FCH_*CN_ + idx] = v;
  }
}

// ---------------------------------------------------------------------------
// K2: per (beta,b,o) row: h = M2 row @ x[b] -> LN -> depthwise conv K -> LN
// ---------------------------------------------------------------------------
__global__ __launch_bounds__(256) void k_front(const float* __restrict__ x,
                                               const float* __restrict__ M2,
                                               FrontPtrs fp,
                                               float* __restrict__ hcat) {
  const int wg   = blockIdx.x;
  const int beta = wg / (B_*FCH_);
  const int rem  = wg - beta*(B_*FCH_);
  const int b    = rem / FCH_;
  const int o    = rem - b*FCH_;
  const int K    = fp.K[beta];
  const int Kh   = K >> 1;

  __shared__ float m2[CN_];
  __shared__ float hb2[T_];
  __shared__ float w5s[80];
  __shared__ float red[8];

  if (threadIdx.x < CN_) m2[threadIdx.x] = M2[(beta*FCH_ + o)*CN_ + threadIdx.x];
  if (threadIdx.x < K)   w5s[threadIdx.x] = fp.w5[beta][o*K + threadIdx.x];
  __syncthreads();

  const float* xb = x + (size_t)b*CN_*T_;
  float hv[4];
  float psum = 0.f;
  #pragma unroll
  for (int e = 0; e < 4; ++e) {
    int t = threadIdx.x + 256*e;
    float acc = 0.f;
    if (t < T_) {
      #pragma unroll
      for (int c = 0; c < CN_; ++c) acc += m2[c] * xb[c*T_ + t];
    }
    hv[e] = acc; psum += acc;
  }
  float mean = block_sum(psum, red) * (1.f/T_);
  float pv = 0.f;
  #pragma unroll
  for (int e = 0; e < 4; ++e) { int t = threadIdx.x + 256*e; if (t < T_) { float d = hv[e]-mean; pv += d*d; } }
  float var = block_sum(pv, red) * (1.f/T_);
  float inv = rsqrtf(var + 1e-5f);
  const float* g1 = fp.g1[beta]; const float* b1 = fp.b1[beta];
  #pragma unroll
  for (int e = 0; e < 4; ++e) { int t = threadIdx.x + 256*e; if (t < T_) hb2[t] = (hv[e]-mean)*inv*g1[t] + b1[t]; }
  __syncthreads();

  float cv[4];
  float ps2 = 0.f;
  #pragma unroll
  for (int e = 0; e < 4; ++e) {
    int t = threadIdx.x + 256*e;
    float acc = 0.f;
    if (t < T_) {
      int lo = t - Kh;
      for (int k = 0; k < K; ++k) {
        int tt = lo + k;
        float hvv = (tt >= 0 && tt < T_) ? hb2[tt] : 0.f;
        acc += hvv * w5s[k];
      }
    }
    cv[e] = acc; ps2 += acc;
  }
  float mean2 = block_sum(ps2, red) * (1.f/T_);
  float pv2 = 0.f;
  #pragma unroll
  for (int e = 0; e < 4; ++e) { int t = threadIdx.x + 256*e; if (t < T_) { float d = cv[e]-mean2; pv2 += d*d; } }
  float var2 = block_sum(pv2, red) * (1.f/T_);
  float inv2 = rsqrtf(var2 + 1e-5f);
  const float* g2 = fp.g2[beta]; const float* b2 = fp.b2[beta];
  float* hrow = hcat + ((size_t)b*(3*FCH_) + beta*FCH_ + o)*T_;
  #pragma unroll
  for (int e = 0; e < 4; ++e) { int t = threadIdx.x + 256*e; if (t < T_) hrow[t] = (cv[e]-mean2)*inv2*g2[t] + b2[t]; }
}

// ---------------------------------------------------------------------------
// K3: h_s = w_sconv @ hcat per b, subtract per-row time mean, store xc.
// ---------------------------------------------------------------------------
__global__ __launch_bounds__(256) void k_sconv(const float* __restrict__ hcat,
                                               const float* __restrict__ wsc,
                                               float* __restrict__ xc) {
  const int b  = blockIdx.x / 10;
  const int s0 = (blockIdx.x % 10) * 10;
  __shared__ float ws[10*450];
  __shared__ float red[8];
  for (int idx = threadIdx.x; idx < 4500; idx += 256) {
    int s = idx / 450, i = idx - s*450;
    ws[idx] = wsc[(s0+s)*450 + i];
  }
  __syncthreads();
  float acc[10][4];
  #pragma unroll
  for (int s = 0; s < 10; ++s)
    #pragma unroll
    for (int e = 0; e < 4; ++e) acc[s][e] = 0.f;
  const float* hb = hcat + (size_t)b*450*T_;
  for (int i = 0; i < 450; ++i) {
    float xv[4];
    #pragma unroll
    for (int e = 0; e < 4; ++e) { int t = threadIdx.x + 256*e; xv[e] = (t < T_) ? hb[(size_t)i*T_ + t] : 0.f; }
    #pragma unroll
    for (int s = 0; s < 10; ++s) {
      float w = ws[s*450 + i];
      #pragma unroll
      for (int e = 0; e < 4; ++e) acc[s][e] += w * xv[e];
    }
  }
  for (int s = 0; s < 10; ++s) {
    float mu = block_sum(acc[s][0]+acc[s][1]+acc[s][2]+acc[s][3], red) * (1.f/T_);
    float* xr = xc + ((size_t)b*SPD_ + s0 + s)*T_;
    #pragma unroll
    for (int e = 0; e < 4; ++e) { int t = threadIdx.x + 256*e; if (t < T_) xr[t] = acc[s][e] - mu; }
  }
}

// ---------------------------------------------------------------------------
// K4a: cov = xc xc^T /999 + 1e-4 I
// ---------------------------------------------------------------------------
__global__ __launch_bounds__(256) void k_cov(const float* __restrict__ xc, float* __restrict__ cov) {
  const int b  = blockIdx.x / 5;
  const int j0 = (blockIdx.x % 5) * 20;
  __shared__ __align__(16) float xst[SPD_*100];
  const int it = threadIdx.x / 10;
  const int jj = threadIdx.x - it*10;
  const bool act = threadIdx.x < 250;
  double a64[4][2] = {{0.0,0.0},{0.0,0.0},{0.0,0.0},{0.0,0.0}};
  for (int ch = 0; ch < 10; ++ch) {
    __syncthreads();
    const int tc0 = ch*100;
    for (int idx = threadIdx.x; idx < SPD_*100; idx += 256) {
      int row = idx / 100, tt = idx - row*100;
      xst[idx] = xc[((size_t)b*SPD_ + row)*T_ + tc0 + tt];
    }
    __syncthreads();
    if (act) {
      float a32[4][2] = {{0,0},{0,0},{0,0},{0,0}};
      for (int t4 = 0; t4 < 100; t4 += 4) {
        float4 xi[4], xj[2];
        #pragma unroll
        for (int r = 0; r < 4; ++r) xi[r] = *(const float4*)&xst[(it + 25*r)*100 + t4];
        #pragma unroll
        for (int s = 0; s < 2; ++s) xj[s] = *(const float4*)&xst[(j0 + jj + 10*s)*100 + t4];
        #pragma unroll
        for (int r = 0; r < 4; ++r)
          #pragma unroll
          for (int s = 0; s < 2; ++s)
            a32[r][s] += xi[r].x*xj[s].x + xi[r].y*xj[s].y + xi[r].z*xj[s].z + xi[r].w*xj[s].w;
      }
      #pragma unroll
      for (int r = 0; r < 4; ++r)
        #pragma unroll
        for (int s = 0; s < 2; ++s) a64[r][s] += (double)a32[r][s];
    }
  }
  if (act) {
    #pragma unroll
    for (int r = 0; r < 4; ++r) {
      #pragma unroll
      for (int s = 0; s < 2; ++s) {
        int i = it + 25*r, j = j0 + jj + 10*s;
        double v = a64[r][s] * (1.0/999.0);
        if (i == j) v += 1e-4;
        cov[(size_t)b*SPD_*SPD_ + i*SPD_ + j] = (float)v;
      }
    }
  }
}

// ---------------------------------------------------------------------------
// K4b: T1 = C @ W^T
// ---------------------------------------------------------------------------
__global__ __launch_bounds__(256) void k_aff1(const float* __restrict__ cov,
                                              const float* __restrict__ waff,
                                              float* __restrict__ T1) {
  const int b  = blockIdx.x / 5;
  const int j0 = (blockIdx.x % 5) * 20;
  __shared__ float Cs[SPD_*101];
  __shared__ float Ws[20*100];
  for (int idx = threadIdx.x; idx < SPD_*SPD_; idx += 256) {
    int r = idx / 100, c = idx - r*100;
    Cs[r*101 + c] = cov[(size_t)b*SPD_*SPD_ + idx];
  }
  for (int idx = threadIdx.x; idx < 2000; idx += 256) {
    int jl = idx / 100, k = idx - jl*100;
    Ws[idx] = waff[(j0+jl)*100 + k];
  }
  __syncthreads();
  if (threadIdx.x < 250) {
    const int it = threadIdx.x / 10, jj = threadIdx.x % 10;
    double acc[4][2] = {{0.0,0.0},{0.0,0.0},{0.0,0.0},{0.0,0.0}};
    for (int k = 0; k < 100; ++k) {
      double cvv[4], wv[2];
      #pragma unroll
      for (int r = 0; r < 4; ++r) cvv[r] = (double)Cs[(it + 25*r)*101 + k];
      #pragma unroll
      for (int s = 0; s < 2; ++s) wv[s] = (double)Ws[(jj + 10*s)*100 + k];
      #pragma unroll
      for (int r = 0; r < 4; ++r)
        #pragma unroll
        for (int s = 0; s < 2; ++s) acc[r][s] += cvv[r]*wv[s];
    }
    #pragma unroll
    for (int r = 0; r < 4; ++r)
      #pragma unroll
      for (int s = 0; s < 2; ++s)
        T1[(size_t)b*SPD_*SPD_ + (it + 25*r)*100 + (j0 + jj + 10*s)] = (float)acc[r][s];
  }
}

// ---------------------------------------------------------------------------
// K4c: P = W @ T1
// ---------------------------------------------------------------------------
__global__ __launch_bounds__(256) void k_aff2(const float* __restrict__ T1,
                                              const float* __restrict__ waff,
                                              float* __restrict__ P) {
  const int b  = blockIdx.x / 5;
  const int j0 = (blockIdx.x % 5) * 20;
  __shared__ float T1s[100*20];
  for (int idx = threadIdx.x; idx < 2000; idx += 256) {
    int k = idx / 20, jl = idx - k*20;
    T1s[idx] = T1[(size_t)b*SPD_*SPD_ + k*100 + j0 + jl];
  }
  __syncthreads();
  if (threadIdx.x < 250) {
    const int it = threadIdx.x / 10, jj = threadIdx.x % 10;
    double acc[4][2] = {{0.0,0.0},{0.0,0.0},{0.0,0.0},{0.0,0.0}};
    for (int k = 0; k < 100; ++k) {
      double wv[4], tv[2];
      #pragma unroll
      for (int r = 0; r < 4; ++r) wv[r] = (double)waff[(it + 25*r)*100 + k];
      #pragma unroll
      for (int s = 0; s < 2; ++s) tv[s] = (double)T1s[k*20 + jj + 10*s];
      #pragma unroll
      for (int r = 0; r < 4; ++r)
        #pragma unroll
        for (int s = 0; s < 2; ++s) acc[r][s] += wv[r]*tv[s];
    }
    #pragma unroll
    for (int r = 0; r < 4; ++r)
      #pragma unroll
      for (int s = 0; s < 2; ++s)
        P[(size_t)b*SPD_*SPD_ + (it + 25*r)*100 + (j0 + jj + 10*s)] = (float)acc[r][s];
  }
}

// ---------------------------------------------------------------------------
// K5: register-resident systolic one-sided Jacobi, DPP migration.
// Continue-threshold |gamma| > 1e-3*sqrt(ab) (residual -> L error ~1e-3,
// inside the 1.34e-2 budget), cap 8 sweeps.
// ---------------------------------------------------------------------------
__global__ __launch_bounds__(256, 1) void k_eig(const float* __restrict__ P,
                                                float* __restrict__ Gout,
                                                double* __restrict__ WCout) {
  __shared__ __align__(16) float G[SPD_*LDSTR];
  __shared__ __align__(16) float gbuf[2][64*4];
  __shared__ __align__(16) float nbuf[64*8];
  __shared__ int fbuf[4];
  const int tid = threadIdx.x;
  const int b   = blockIdx.x;
  const int w   = tid >> 6;
  const int j   = tid & 63;
  const bool act = (j < 50);
  const int rb  = 25 * w;

  float A[25], B[25];
  const float* Pb = P + (size_t)b*SPD_*SPD_;
  #pragma unroll
  for (int i = 0; i < 25; ++i) {
    A[i] = act ? Pb[(rb+i)*SPD_ + j]      : 0.f;
    B[i] = act ? Pb[(rb+i)*SPD_ + (99-j)] : 0.f;
  }
  float pA = 0.f, pB = 0.f;
  #pragma unroll
  for (int i = 0; i < 25; ++i) { pA += A[i]*A[i]; pB += B[i]*B[i]; }
  nbuf[j*8 + w*2 + 0] = pA;
  nbuf[j*8 + w*2 + 1] = pB;
  __syncthreads();
  float nA, nB;
  {
    float4 u0 = *(const float4*)&nbuf[j*8];
    float4 u1 = *(const float4*)&nbuf[j*8+4];
    nA = (u0.x + u0.z) + (u1.x + u1.z);
    nB = (u0.y + u0.w) + (u1.y + u1.w);
  }
  float pg = 0.f;
  #pragma unroll
  for (int i = 0; i < 25; ++i) pg += A[i]*B[i];

  int par = 0;
  for (int sweep = 0; sweep < MAXSWEEP; ++sweep) {
    int swflag = 0;
    for (int r = 0; r < 99; ++r) {
      gbuf[par][j*4 + w] = pg;
      __syncthreads();                       // the ONLY barrier per round
      float4 gp = *(const float4*)&gbuf[par][j*4];
      float gamma = (gp.x + gp.y) + (gp.z + gp.w);

      float cr = 1.f, sr = 0.f;
      float g2 = gamma*gamma;
      float ab = nA*nB;
      if (act && g2 > 1e-12f*ab) {           // rotate if |g| > 1e-6*sqrt(ab)
        if (g2 > 1e-6f*ab) swflag = 1;       // continue if |g| > 1e-3*sqrt(ab)
        float tau = (nB - nA) / (2.f*gamma);
        float t = ((tau >= 0.f) ? 1.f : -1.f) / (fabsf(tau) + sqrtf(1.f + tau*tau));
        cr = rsqrtf(1.f + t*t);
        sr = t*cr;
        nA = nA - t*gamma;
        nB = nB + t*gamma;
      }
      // norm migration (DPP)
      {
        float sendN = (j == 0) ? nB : nA;
        float rNA = dpp_shr1(nA, sendN);     // lane0 keeps old nA
        float rNB = dpp_shl1(nB, nB);        // lane63 keeps old (garbage ok)
        float newB = (j == 49) ? nA : rNB;
        nA = rNA; nB = newB;
      }
      // fused rotate + DPP migrate + next-round partial gamma
      pg = 0.f;
      #pragma unroll
      for (int i = 0; i < 25; ++i) {
        float na = cr*A[i] - sr*B[i];
        float nb = sr*A[i] + cr*B[i];
        float sendA = (j == 0) ? nb : na;
        float rA = dpp_shr1(na, sendA);      // lane0 keeps na
        float rB = dpp_shl1(nb, nb);         // lane63 keeps old (garbage ok)
        A[i] = rA;
        B[i] = (j == 49) ? na : rB;
        pg += A[i]*B[i];
      }
      par ^= 1;
    }
    unsigned long long any = __ballot(swflag);
    if (j == 0) fbuf[w] = (any != 0ull) ? 1 : 0;
    __syncthreads();
    int f = fbuf[0] | fbuf[1] | fbuf[2] | fbuf[3];
    __syncthreads();
    if (!f) break;
  }

  // dump converged columns to LDS (seat order; order irrelevant for the sum)
  if (act) {
    #pragma unroll
    for (int i = 0; i < 25; ++i) {
      G[j*LDSTR + rb + i]        = A[i];
      G[(50 + j)*LDSTR + rb + i] = B[i];
    }
  }
  __syncthreads();

  // exact fp64 column norms -> wc = log(clip(lam,1e-6)) / lam^2 ; write out
  if (tid < SPD_) {
    const float* col = &G[tid*LDSTR];
    double s = 0.0;
    for (int i = 0; i < SPD_; ++i) { double v = (double)col[i]; s += v*v; }
    double lam = sqrt(s);
    double lc  = (lam < 1e-6) ? 1e-6 : lam;
    WCout[b*SPD_ + tid] = log(lc) / ((s > 1e-300) ? s : 1e-300);
  }
  // coalesced dump of G to workspace (col-major, stride 100)
  for (int idx = tid; idx < SPD_*SPD_; idx += 256) {
    int c = idx / SPD_, i = idx - c*SPD_;
    Gout[(size_t)b*SPD_*SPD_ + idx] = G[c*LDSTR + i];
  }
}

// ---------------------------------------------------------------------------
// K5b: L = sum_c wc[c] * g_c g_c^T ; scaled upper-tri -> out[64 + b*5050 + idx]
// ---------------------------------------------------------------------------
__global__ __launch_bounds__(256) void k_lout(const float* __restrict__ Gin,
                                              const double* __restrict__ WCin,
                                              float* __restrict__ out) {
  __shared__ __align__(16) float G[SPD_*SPD_];
  __shared__ float wcs[SPD_];
  const int tid = threadIdx.x;
  const int b   = blockIdx.x;
  for (int idx = tid; idx < SPD_*SPD_; idx += 256)
    G[idx] = Gin[(size_t)b*SPD_*SPD_ + idx];
  if (tid < SPD_) wcs[tid] = (float)WCin[b*SPD_ + tid];
  __syncthreads();

  for (int tile = tid; tile < 625; tile += 256) {
    const int ti = (tile / 25) * 4;
    const int tj = (tile % 25) * 4;
    float acc[4][4];
    #pragma unroll
    for (int r = 0; r < 4; ++r)
      #pragma unroll
      for (int s = 0; s < 4; ++s) acc[r][s] = 0.f;
    for (int c = 0; c < SPD_; ++c) {
      const float* col = &G[c*SPD_];
      float4 ga = *(const float4*)&col[ti];
      float4 gb = *(const float4*)&col[tj];
      float wcv = wcs[c];
      float wa[4] = { wcv*ga.x, wcv*ga.y, wcv*ga.z, wcv*ga.w };
      float bv[4] = { gb.x, gb.y, gb.z, gb.w };
      #pragma unroll
      for (int r = 0; r < 4; ++r)
        #pragma unroll
        for (int s = 0; s < 4; ++s) acc[r][s] += wa[r]*bv[s];
    }
    const float RT2 = 1.41421356237309505f;
    #pragma unroll
    for (int r = 0; r < 4; ++r) {
      #pragma unroll
      for (int s = 0; s < 4; ++s) {
        int i = ti + r, jx = tj + s;
        if (i <= jx) {
          int idx = i*SPD_ - (i*(i+1))/2 + jx;
          out[64 + b*5050 + idx] = acc[r][s] * (i == jx ? 1.f : RT2);
        }
      }
    }
  }
}

// ---------------------------------------------------------------------------
// K6: logits = flat @ w_fc^T + b_fc
// ---------------------------------------------------------------------------
__global__ __launch_bounds__(256) void k_fc(const float* __restrict__ wfc,
                                            const float* __restrict__ bfc,
                                            float* __restrict__ out) {
  __shared__ float red[8];
  const int b = blockIdx.x;
  const float* flat = out + 64 + b*5050;
  float a0 = 0.f, a1 = 0.f, a2 = 0.f, a3 = 0.f;
  for (int k = threadIdx.x; k < 5050; k += 256) {
    float f = flat[k];
    a0 += f * wfc[k];
    a1 += f * wfc[5050 + k];
    a2 += f * wfc[10100 + k];
    a3 += f * wfc[15150 + k];
  }
  a0 = block_sum(a0, red);
  a1 = block_sum(a1, red);
  a2 = block_sum(a2, red);
  a3 = block_sum(a3, red);
  if (threadIdx.x == 0) {
    out[b*4 + 0] = a0 + bfc[0];
    out[b*4 + 1] = a1 + bfc[1];
    out[b*4 + 2] = a2 + bfc[2];
    out[b*4 + 3] = a3 + bfc[3];
  }
}

extern "C" void kernel_launch(void* const* d_in, const int* in_sizes, int n_in,
                              void* d_out, int out_size, void* d_ws, size_t ws_size,
                              hipStream_t stream) {
  (void)in_sizes; (void)n_in; (void)out_size; (void)ws_size;
  const float* x = (const float*)d_in[0];
  const float* bw[3][9];
  for (int i = 0; i < 3; ++i)
    for (int jx = 0; jx < 9; ++jx)
      bw[i][jx] = (const float*)d_in[1 + i*9 + jx];
  const float* w_sconv = (const float*)d_in[28];
  const float* w_aff   = (const float*)d_in[29];
  const float* w_fc    = (const float*)d_in[30];
  const float* b_fc    = (const float*)d_in[31];

  char* ws = (char*)d_ws;
  float*  M2   = (float*)(ws + OFF_M2);
  float*  hcat = (float*)(ws + OFF_HCAT);
  float*  xc   = (float*)(ws + OFF_XC);
  float*  cov  = (float*)(ws + OFF_COV);
  float*  T1   = (float*)(ws + OFF_T1);
  float*  P    = (float*)(ws + OFF_P);
  float*  G    = (float*)(ws + OFF_G);    // reuses xc region (dead after k_cov)
  double* WC   = (double*)(ws + OFF_WC);
  float*  out  = (float*)d_out;

  PrepPtrs pp; FrontPtrs fp;
  for (int i = 0; i < 3; ++i) {
    pp.w1[i] = bw[i][0]; pp.w2[i] = bw[i][1]; pp.w3[i] = bw[i][2]; pp.w4[i] = bw[i][3];
    fp.g1[i] = bw[i][4]; fp.b1[i] = bw[i][5]; fp.w5[i] = bw[i][6];
    fp.g2[i] = bw[i][7]; fp.b2[i] = bw[i][8];
  }
  fp.K[0] = 15; fp.K[1] = 75; fp.K[2] = 55;

  hipLaunchKernelGGL(k_prep,  dim3(3),            dim3(256), 0, stream, pp, M2);
  hipLaunchKernelGGL(k_front, dim3(3*B_*FCH_),    dim3(256), 0, stream, x, M2, fp, hcat);
  hipLaunchKernelGGL(k_sconv, dim3(B_*10),        dim3(256), 0, stream, hcat, w_sconv, xc);
  hipLaunchKernelGGL(k_cov,   dim3(B_*5),         dim3(256), 0, stream, xc, cov);
  hipLaunchKernelGGL(k_aff1,  dim3(B_*5),         dim3(256), 0, stream, cov, w_aff, T1);
  hipLaunchKernelGGL(k_aff2,  dim3(B_*5),         dim3(256), 0, stream, T1, w_aff, P);
  hipLaunchKernelGGL(k_eig,   dim3(B_),           dim3(256), 0, stream, P, G, WC);
  hipLaunchKernelGGL(k_lout,  dim3(B_),           dim3(256), 0, stream, G, WC, out);
  hipLaunchKernelGGL(k_fc,    dim3(B_),           dim3(256), 0, stream, w_fc, b_fc, out);
}